// Round 1
// 320.160 us; speedup vs baseline: 1.0337x; 1.0337x over previous
//
#include <hip/hip_runtime.h>

namespace {
constexpr int HD  = 128;
constexpr int NH  = 32;
constexpr int NKV = 8;
constexpr int SEQ = 8192;
constexpr int ROW = NH * HD + 2 * NKV * HD;          // 6144 floats per qkv row
constexpr int QK_HEADS = NH + NKV;                   // 40 heads, contiguous per row
constexpr int HEADS_PER_WAVE = 4;                    // 16 lanes per head
constexpr int WAVES_PER_TOKEN = QK_HEADS / HEADS_PER_WAVE;   // 10
constexpr int QK_WAVES  = SEQ * WAVES_PER_TOKEN;     // 81920
constexpr int QK_BLOCKS = QK_WAVES / 4;              // 20480 (4 waves/block)
constexpr long long Q_OUT = (long long)SEQ * NH * HD;    // 33554432 floats
constexpr long long K_OUT = (long long)SEQ * NKV * HD;   //  8388608 floats
constexpr int V_ELEMS  = SEQ * NKV * HD;             // 8388608 floats
constexpr int V_CHUNKS = V_ELEMS / 4;                // 2097152 float4 chunks
constexpr int V_BLOCKS = V_CHUNKS / 256;             // 8192
constexpr float EPS = 1e-6f;
typedef float f4 __attribute__((ext_vector_type(4)));
}

// QK blocks: 16 lanes per head. Each lane owns float4 at d and at d+64 of the
// SAME head, so the rotate-half partner is in-lane (0 shuffles) and the RMS
// reduce is a 4-step 16-lane shfl_xor. 2 independent load streams per lane
// (2x ILP vs previous 1), half the wave count. Streaming data (qkv rows, out)
// uses nontemporal loads/stores — every byte touched exactly once.
// V blocks: pass-through float4 copy, nontemporal both ways.
__global__ __launch_bounds__(256) void qknorm_rope_kernel(
    const float* __restrict__ qkv,
    const float* __restrict__ qw,
    const float* __restrict__ kw,
    const float* __restrict__ cw,
    const float* __restrict__ sw,
    float* __restrict__ out)
{
    const int bid = blockIdx.x;
    const int tid = threadIdx.x;

    if (bid < QK_BLOCKS) {
        const int lane = tid & 63;
        const int W    = bid * 4 + (tid >> 6);      // global wave id
        const int t    = W / WAVES_PER_TOKEN;       // token
        const int jg   = W - t * WAVES_PER_TOKEN;   // head-quad index (0..9)
        const int head = jg * HEADS_PER_WAVE + (lane >> 4);  // 0..39, wave-uniform q/k
        const int dlo  = (lane & 15) * 4;           // 0..60, element base (lower half)

        const float* src = qkv + (long long)t * ROW + head * HD + dlo;
        const f4 xl = __builtin_nontemporal_load((const f4*)src);         // d in [0,64)
        const f4 xh = __builtin_nontemporal_load((const f4*)(src + 64));  // d in [64,128)

        float ss = 0.f;
        #pragma unroll
        for (int i = 0; i < 4; ++i) ss += xl[i] * xl[i] + xh[i] * xh[i];
        #pragma unroll
        for (int m = 1; m < 16; m <<= 1) ss += __shfl_xor(ss, m, 64);
        const float inv = rsqrtf(ss * (1.0f / HD) + EPS);

        const float* wp = (head < NH) ? qw : kw;    // wave-uniform (jg<=7 all q, jg>=8 all k)
        const f4 wl = *(const f4*)(wp + dlo);
        const f4 wh = *(const f4*)(wp + dlo + 64);
        const f4 cl = *(const f4*)(cw + dlo);
        const f4 ch = *(const f4*)(cw + dlo + 64);
        const f4 sl = *(const f4*)(sw + dlo);
        const f4 sh = *(const f4*)(sw + dlo + 64);

        // d < 64:  o = qn*cos - qn[d+64]*sin
        // d >= 64: o = qn*cos + qn[d-64]*sin
        f4 ol, oh;
        #pragma unroll
        for (int i = 0; i < 4; ++i) {
            const float ql = xl[i] * inv * wl[i];
            const float qh = xh[i] * inv * wh[i];
            ol[i] = ql * cl[i] - qh * sl[i];
            oh[i] = qh * ch[i] + ql * sh[i];
        }

        long long dst;
        if (head < NH) dst = (long long)t * (NH * HD) + head * HD + dlo;
        else           dst = Q_OUT + (long long)t * (NKV * HD) + (head - NH) * HD + dlo;
        __builtin_nontemporal_store(ol, (f4*)(out + dst));
        __builtin_nontemporal_store(oh, (f4*)(out + dst + 64));
    } else {
        // v copy: chunk = 4 floats; 256 chunks per token row (1024 floats)
        const int cidx = (bid - QK_BLOCKS) * 256 + tid;
        const int t    = cidx >> 8;
        const int col  = cidx & 255;
        const f4 v = __builtin_nontemporal_load(
            (const f4*)(qkv + (long long)t * ROW + (NH + NKV) * HD + col * 4));
        __builtin_nontemporal_store(v, (f4*)(out + Q_OUT + K_OUT + (long long)cidx * 4));
    }
}

extern "C" void kernel_launch(void* const* d_in, const int* in_sizes, int n_in,
                              void* d_out, int out_size, void* d_ws, size_t ws_size,
                              hipStream_t stream) {
    const float* qkv = (const float*)d_in[0];
    const float* qw  = (const float*)d_in[1];
    const float* kw  = (const float*)d_in[2];
    const float* cw  = (const float*)d_in[3];
    const float* sw  = (const float*)d_in[4];
    float* out = (float*)d_out;

    qknorm_rope_kernel<<<QK_BLOCKS + V_BLOCKS, 256, 0, stream>>>(qkv, qw, kw, cw, sw, out);
}

// Round 2
// 319.034 us; speedup vs baseline: 1.0374x; 1.0035x over previous
//
#include <hip/hip_runtime.h>

namespace {
constexpr int HD  = 128;
constexpr int NH  = 32;
constexpr int NKV = 8;
constexpr int SEQ = 8192;
constexpr int ROW = NH * HD + 2 * NKV * HD;          // 6144 floats per qkv row
constexpr int QK_HEADS = NH + NKV;                   // 40 heads, contiguous per row
constexpr int HEADS_PER_WAVE = 4;                    // 16 lanes per head
constexpr int WAVES_PER_TOKEN = QK_HEADS / HEADS_PER_WAVE;   // 10
constexpr int QK_WAVES  = SEQ * WAVES_PER_TOKEN;     // 81920
constexpr int QK_BLOCKS = QK_WAVES / 4;              // 20480 (4 waves/block)
constexpr long long Q_OUT = (long long)SEQ * NH * HD;    // 33554432 floats
constexpr long long K_OUT = (long long)SEQ * NKV * HD;   //  8388608 floats
constexpr int V_ELEMS  = SEQ * NKV * HD;             // 8388608 floats
constexpr int V_CHUNKS = V_ELEMS / 4;                // 2097152 float4 chunks
constexpr int V_BLOCKS = V_CHUNKS / 256;             // 8192
// Interleave: group = 2 tokens = 5 QK blocks + 2 V blocks, so the V read of a
// token row dispatches adjacent in time to its QK reads -> one sequential HBM
// sweep instead of two passes (QK phase then V phase) over every DRAM page.
constexpr int GROUPS = SEQ / 2;                      // 4096 groups of 7 blocks
constexpr float EPS = 1e-6f;
typedef float f4 __attribute__((ext_vector_type(4)));
}

// QK work: 16 lanes per head. Each lane owns float4 at d and at d+64 of the
// SAME head, so the rotate-half partner is in-lane (0 shuffles) and the RMS
// reduce is a 4-step 16-lane shfl_xor. Streaming data uses nontemporal
// loads/stores — every byte touched exactly once.
// V work: pass-through float4 copy, nontemporal both ways.
__global__ __launch_bounds__(256) void qknorm_rope_kernel(
    const float* __restrict__ qkv,
    const float* __restrict__ qw,
    const float* __restrict__ kw,
    const float* __restrict__ cw,
    const float* __restrict__ sw,
    float* __restrict__ out)
{
    const int bid = blockIdx.x;
    const int tid = threadIdx.x;

    // bid -> (group g, role r): r in [0,5) = QK block g*5+r; r in {5,6} = V block g*2+(r-5)
    const int g = bid / 7;
    const int r = bid - g * 7;

    if (r < 5) {
        const int qkb  = g * 5 + r;                 // [0, QK_BLOCKS)
        const int lane = tid & 63;
        const int W    = qkb * 4 + (tid >> 6);      // global wave id
        const int t    = W / WAVES_PER_TOKEN;       // token
        const int jg   = W - t * WAVES_PER_TOKEN;   // head-quad index (0..9)
        const int head = jg * HEADS_PER_WAVE + (lane >> 4);  // 0..39, wave-uniform q/k
        const int dlo  = (lane & 15) * 4;           // 0..60, element base (lower half)

        const float* src = qkv + (long long)t * ROW + head * HD + dlo;
        const f4 xl = __builtin_nontemporal_load((const f4*)src);         // d in [0,64)
        const f4 xh = __builtin_nontemporal_load((const f4*)(src + 64));  // d in [64,128)

        float ss = 0.f;
        #pragma unroll
        for (int i = 0; i < 4; ++i) ss += xl[i] * xl[i] + xh[i] * xh[i];
        #pragma unroll
        for (int m = 1; m < 16; m <<= 1) ss += __shfl_xor(ss, m, 64);
        const float inv = rsqrtf(ss * (1.0f / HD) + EPS);

        const float* wp = (head < NH) ? qw : kw;    // wave-uniform (jg<=7 all q, jg>=8 all k)
        const f4 wl = *(const f4*)(wp + dlo);
        const f4 wh = *(const f4*)(wp + dlo + 64);
        const f4 cl = *(const f4*)(cw + dlo);
        const f4 ch = *(const f4*)(cw + dlo + 64);
        const f4 sl = *(const f4*)(sw + dlo);
        const f4 sh = *(const f4*)(sw + dlo + 64);

        // d < 64:  o = qn*cos - qn[d+64]*sin
        // d >= 64: o = qn*cos + qn[d-64]*sin
        f4 ol, oh;
        #pragma unroll
        for (int i = 0; i < 4; ++i) {
            const float ql = xl[i] * inv * wl[i];
            const float qh = xh[i] * inv * wh[i];
            ol[i] = ql * cl[i] - qh * sl[i];
            oh[i] = qh * ch[i] + ql * sh[i];
        }

        long long dst;
        if (head < NH) dst = (long long)t * (NH * HD) + head * HD + dlo;
        else           dst = Q_OUT + (long long)t * (NKV * HD) + (head - NH) * HD + dlo;
        __builtin_nontemporal_store(ol, (f4*)(out + dst));
        __builtin_nontemporal_store(oh, (f4*)(out + dst + 64));
    } else {
        // v copy: one block = one token row's V (256 float4 chunks = 1024 floats)
        const int vb   = g * 2 + (r - 5);           // [0, V_BLOCKS)
        const int cidx = vb * 256 + tid;
        const int t    = cidx >> 8;
        const int col  = cidx & 255;
        const f4 v = __builtin_nontemporal_load(
            (const f4*)(qkv + (long long)t * ROW + (NH + NKV) * HD + col * 4));
        __builtin_nontemporal_store(v, (f4*)(out + Q_OUT + K_OUT + (long long)cidx * 4));
    }
}

extern "C" void kernel_launch(void* const* d_in, const int* in_sizes, int n_in,
                              void* d_out, int out_size, void* d_ws, size_t ws_size,
                              hipStream_t stream) {
    const float* qkv = (const float*)d_in[0];
    const float* qw  = (const float*)d_in[1];
    const float* kw  = (const float*)d_in[2];
    const float* cw  = (const float*)d_in[3];
    const float* sw  = (const float*)d_in[4];
    float* out = (float*)d_out;

    qknorm_rope_kernel<<<GROUPS * 7, 256, 0, stream>>>(qkv, qw, kw, cw, sw, out);
}